// Round 1
// baseline (1828.512 us; speedup 1.0000x reference)
//
#include <hip/hip_runtime.h>
#include <math.h>

#define D_MODEL 512
#define N_HEADS 8
#define D_K     64
#define D_EDGE  16
#define D_FF    2048
#define B_SZ    4
#define N_SEQ   1024
#define M_ROWS  (B_SZ * N_SEQ)
#define LN_EPS  1e-5f

#define TI 32
#define TJ 16
#define JSPLIT 4
#define PAIRS (B_SZ * N_HEADS * N_SEQ)   // 32768

__device__ __forceinline__ float gelu_exact(float v) {
  return 0.5f * v * (1.0f + erff(v * 0.70710678118654752440f));
}

// ---------------- LayerNorm: one wave per row ----------------
__global__ __launch_bounds__(256) void ln_kernel(
    const float* __restrict__ x, const float* __restrict__ g,
    const float* __restrict__ bb, float* __restrict__ out)
{
  const int row  = blockIdx.x * 4 + (threadIdx.x >> 6);
  const int lane = threadIdx.x & 63;
  const float4* xr = (const float4*)(x + (size_t)row * D_MODEL);
  float4 v0 = xr[lane * 2 + 0];
  float4 v1 = xr[lane * 2 + 1];
  float s  = v0.x + v0.y + v0.z + v0.w + v1.x + v1.y + v1.z + v1.w;
  float ss = v0.x*v0.x + v0.y*v0.y + v0.z*v0.z + v0.w*v0.w
           + v1.x*v1.x + v1.y*v1.y + v1.z*v1.z + v1.w*v1.w;
  #pragma unroll
  for (int off = 32; off >= 1; off >>= 1) {
    s  += __shfl_xor(s, off);
    ss += __shfl_xor(ss, off);
  }
  const float mu  = s * (1.0f / D_MODEL);
  const float var = ss * (1.0f / D_MODEL) - mu * mu;
  const float r   = rsqrtf(var + LN_EPS);
  const float4* gp = (const float4*)g;
  const float4* bp = (const float4*)bb;
  float4 g0 = gp[lane*2+0], g1v = gp[lane*2+1];
  float4 b0 = bp[lane*2+0], b1v = bp[lane*2+1];
  float4 o0, o1;
  o0.x = (v0.x - mu) * r * g0.x + b0.x;
  o0.y = (v0.y - mu) * r * g0.y + b0.y;
  o0.z = (v0.z - mu) * r * g0.z + b0.z;
  o0.w = (v0.w - mu) * r * g0.w + b0.w;
  o1.x = (v1.x - mu) * r * g1v.x + b1v.x;
  o1.y = (v1.y - mu) * r * g1v.y + b1v.y;
  o1.z = (v1.z - mu) * r * g1v.z + b1v.z;
  o1.w = (v1.w - mu) * r * g1v.w + b1v.w;
  float4* orow = (float4*)(out + (size_t)row * D_MODEL);
  orow[lane*2+0] = o0;
  orow[lane*2+1] = o1;
}

// ---------------- Tiled fp32 GEMM: C[M][Nout] = A[M][K] @ W[Nout][K]^T ----------------
// BM=128, BN=64, BK=16, 256 threads, 8x4 per-thread tile.
template <int ACT, bool RES>
__global__ __launch_bounds__(256) void gemm_kernel(
    const float* __restrict__ A, const float* __restrict__ W,
    const float* __restrict__ bias, const float* __restrict__ res,
    float* __restrict__ C, int M, int Nout, int K)
{
  __shared__ float As[16][132];   // padded: stride 132 (16B-aligned rows, conflict-light)
  __shared__ float Ws[16][68];
  const int tid  = threadIdx.x;
  const int row0 = blockIdx.x * 128;
  const int col0 = blockIdx.y * 64;
  const int ty = tid >> 4;   // 0..15 -> rows ty*8..+8
  const int tx = tid & 15;   // 0..15 -> cols tx*4..+4
  float acc[8][4] = {};

  for (int k0 = 0; k0 < K; k0 += 16) {
    #pragma unroll
    for (int lp = 0; lp < 2; ++lp) {
      const int idx = tid + lp * 256;       // 512 float4 = 128 rows x 16 k
      const int r = idx >> 2, kq = idx & 3;
      const float4 a = *(const float4*)(A + (size_t)(row0 + r) * K + k0 + kq * 4);
      As[kq*4+0][r] = a.x; As[kq*4+1][r] = a.y;
      As[kq*4+2][r] = a.z; As[kq*4+3][r] = a.w;
    }
    {
      const int r = tid >> 2, kq = tid & 3; // 256 float4 = 64 rows x 16 k
      const float4 w = *(const float4*)(W + (size_t)(col0 + r) * K + k0 + kq * 4);
      Ws[kq*4+0][r] = w.x; Ws[kq*4+1][r] = w.y;
      Ws[kq*4+2][r] = w.z; Ws[kq*4+3][r] = w.w;
    }
    __syncthreads();
    #pragma unroll
    for (int kk = 0; kk < 16; ++kk) {
      const float4 a0 = *(const float4*)&As[kk][ty*8 + 0];
      const float4 a1 = *(const float4*)&As[kk][ty*8 + 4];
      const float4 w4 = *(const float4*)&Ws[kk][tx*4];
      const float am[8] = {a0.x, a0.y, a0.z, a0.w, a1.x, a1.y, a1.z, a1.w};
      const float wn[4] = {w4.x, w4.y, w4.z, w4.w};
      #pragma unroll
      for (int mm = 0; mm < 8; ++mm)
        #pragma unroll
        for (int nn = 0; nn < 4; ++nn)
          acc[mm][nn] = fmaf(am[mm], wn[nn], acc[mm][nn]);
    }
    __syncthreads();
  }

  float4 bs = make_float4(0.f, 0.f, 0.f, 0.f);
  if (bias) bs = *(const float4*)(bias + col0 + tx * 4);
  #pragma unroll
  for (int mm = 0; mm < 8; ++mm) {
    const int rr = row0 + ty * 8 + mm;
    float4 v;
    v.x = acc[mm][0] + bs.x; v.y = acc[mm][1] + bs.y;
    v.z = acc[mm][2] + bs.z; v.w = acc[mm][3] + bs.w;
    if (ACT == 1) {
      v.x = gelu_exact(v.x); v.y = gelu_exact(v.y);
      v.z = gelu_exact(v.z); v.w = gelu_exact(v.w);
    }
    if (RES) {
      const float4 rv = *(const float4*)(res + (size_t)rr * Nout + col0 + tx * 4);
      v.x += rv.x; v.y += rv.y; v.z += rv.z; v.w += rv.w;
    }
    *(float4*)(C + (size_t)rr * Nout + col0 + tx * 4) = v;
  }
}

// ---------------- Fused flash attention with edge bias ----------------
// grid = JSPLIT * (N/TI) * B blocks, 256 threads = 8 heads x 32 i-rows.
// Each thread owns one (h, i) row: Q and O accumulator in registers,
// online softmax over its j-range. Edge bias computed cooperatively once
// per (i,j) pair for all 8 heads (edge_emb read exactly once from HBM).
// K/V read directly from global (L2-resident: 4 MiB per batch).
__global__ __launch_bounds__(256) void attn_kernel(
    const float* __restrict__ Qm, const float* __restrict__ Km,
    const float* __restrict__ Vm, const float* __restrict__ edge,
    const unsigned char* __restrict__ mask,
    const float* __restrict__ we, const float* __restrict__ web,
    float* __restrict__ pm, float* __restrict__ pl, float* __restrict__ pacc)
{
  __shared__ float we_s[N_HEADS][D_EDGE];
  __shared__ float web_s[N_HEADS];
  __shared__ float bias_s[N_HEADS][TI][TJ + 1];  // +1 pad: conflict-free reads

  const int blk   = blockIdx.x;
  const int split = blk & (JSPLIT - 1);
  const int it    = (blk >> 2) & 31;
  const int b     = blk >> 7;
  const int tid   = threadIdx.x;
  const int h     = tid >> 5;
  const int il    = tid & 31;
  const int i     = it * TI + il;

  if (tid < N_HEADS * D_EDGE) we_s[tid >> 4][tid & 15] = we[tid];
  if (tid < N_HEADS) web_s[tid] = web[tid];

  float4 qreg[16];
  {
    const float4* qp = (const float4*)(Qm + (size_t)(b * N_SEQ + i) * D_MODEL + h * D_K);
    #pragma unroll
    for (int d = 0; d < 16; ++d) qreg[d] = qp[d];
  }
  float m = -INFINITY, l = 0.0f;
  float4 acc4[16];
  #pragma unroll
  for (int d = 0; d < 16; ++d) acc4[d] = make_float4(0.f, 0.f, 0.f, 0.f);

  const float scale = 0.125f;   // 1/sqrt(64)
  const int j0base = split * (N_SEQ / JSPLIT);

  for (int jc = 0; jc < (N_SEQ / JSPLIT) / TJ; ++jc) {
    const int j0 = j0base + jc * TJ;
    __syncthreads();
    // cooperative edge-bias tile: 32 i x 16 j pairs, one thread per pair (x2)
    #pragma unroll
    for (int lp = 0; lp < 2; ++lp) {
      const int p  = tid + lp * 256;
      const int pi = p >> 4, pj = p & 15;
      const int j  = j0 + pj;
      const float4* ep = (const float4*)(edge +
          ((((size_t)b * N_SEQ) + (it * TI + pi)) * N_SEQ + j) * D_EDGE);
      const float4 e0 = ep[0], e1 = ep[1], e2 = ep[2], e3 = ep[3];
      const float mk = (mask[b * N_SEQ + j] != 0) ? 0.0f : -INFINITY;
      #pragma unroll
      for (int hh = 0; hh < N_HEADS; ++hh) {
        float d =
            e0.x*we_s[hh][0]  + e0.y*we_s[hh][1]  + e0.z*we_s[hh][2]  + e0.w*we_s[hh][3]
          + e1.x*we_s[hh][4]  + e1.y*we_s[hh][5]  + e1.z*we_s[hh][6]  + e1.w*we_s[hh][7]
          + e2.x*we_s[hh][8]  + e2.y*we_s[hh][9]  + e2.z*we_s[hh][10] + e2.w*we_s[hh][11]
          + e3.x*we_s[hh][12] + e3.y*we_s[hh][13] + e3.z*we_s[hh][14] + e3.w*we_s[hh][15]
          + web_s[hh];
        bias_s[hh][pi][pj] = d + mk;
      }
    }
    __syncthreads();

    float sc[TJ];
    #pragma unroll
    for (int jl = 0; jl < TJ; ++jl) {
      const float4* kp = (const float4*)(Km + (size_t)(b * N_SEQ + j0 + jl) * D_MODEL + h * D_K);
      float s = 0.f;
      #pragma unroll
      for (int d = 0; d < 16; ++d) {
        const float4 kv = kp[d];
        s += qreg[d].x*kv.x + qreg[d].y*kv.y + qreg[d].z*kv.z + qreg[d].w*kv.w;
      }
      sc[jl] = s * scale + bias_s[h][il][jl];
    }
    float tm = sc[0];
    #pragma unroll
    for (int jl = 1; jl < TJ; ++jl) tm = fmaxf(tm, sc[jl]);
    const float nm = fmaxf(m, tm);
    const float alpha = (m == nm) ? 1.0f : __expf(m - nm);
    l *= alpha;
    #pragma unroll
    for (int d = 0; d < 16; ++d) {
      acc4[d].x *= alpha; acc4[d].y *= alpha;
      acc4[d].z *= alpha; acc4[d].w *= alpha;
    }
    #pragma unroll
    for (int jl = 0; jl < TJ; ++jl) {
      const float p = (sc[jl] == -INFINITY) ? 0.0f : __expf(sc[jl] - nm);
      l += p;
      const float4* vp = (const float4*)(Vm + (size_t)(b * N_SEQ + j0 + jl) * D_MODEL + h * D_K);
      #pragma unroll
      for (int d = 0; d < 16; ++d) {
        const float4 vv = vp[d];
        acc4[d].x = fmaf(p, vv.x, acc4[d].x);
        acc4[d].y = fmaf(p, vv.y, acc4[d].y);
        acc4[d].z = fmaf(p, vv.z, acc4[d].z);
        acc4[d].w = fmaf(p, vv.w, acc4[d].w);
      }
    }
    m = nm;
  }

  const size_t idx = ((((size_t)split * B_SZ + b) * N_HEADS) + h) * N_SEQ + i;
  pm[idx] = m;
  pl[idx] = l;
  float4* pa = (float4*)(pacc + idx * D_K);
  #pragma unroll
  for (int d = 0; d < 16; ++d) pa[d] = acc4[d];
}

// ---------------- Merge JSPLIT partial softmax states ----------------
__global__ __launch_bounds__(256) void attn_merge_kernel(
    const float* __restrict__ pm, const float* __restrict__ pl,
    const float* __restrict__ pacc, float* __restrict__ out)
{
  const int idx = blockIdx.x * 256 + threadIdx.x;   // (b*8+h)*1024 + i
  const int i = idx & (N_SEQ - 1);
  const int h = (idx >> 10) & (N_HEADS - 1);
  const int b = idx >> 13;
  float ms[JSPLIT], ls[JSPLIT];
  float M = -INFINITY;
  #pragma unroll
  for (int s = 0; s < JSPLIT; ++s) {
    ms[s] = pm[(size_t)s * PAIRS + idx];
    ls[s] = pl[(size_t)s * PAIRS + idx];
    M = fmaxf(M, ms[s]);
  }
  float w[JSPLIT];
  float L = 0.f;
  #pragma unroll
  for (int s = 0; s < JSPLIT; ++s) {
    w[s] = (ms[s] == -INFINITY) ? 0.0f : __expf(ms[s] - M);
    L += ls[s] * w[s];
  }
  const float inv = (L > 0.f) ? 1.0f / L : 0.0f;   // fully-masked row -> zeros
  float* orow = out + (size_t)(b * N_SEQ + i) * D_MODEL + h * D_K;
  #pragma unroll
  for (int d4 = 0; d4 < 16; ++d4) {
    float4 o = make_float4(0.f, 0.f, 0.f, 0.f);
    #pragma unroll
    for (int s = 0; s < JSPLIT; ++s) {
      const float4 a = *(const float4*)(pacc + ((size_t)s * PAIRS + idx) * D_K + d4 * 4);
      o.x = fmaf(w[s], a.x, o.x);
      o.y = fmaf(w[s], a.y, o.y);
      o.z = fmaf(w[s], a.z, o.z);
      o.w = fmaf(w[s], a.w, o.w);
    }
    o.x *= inv; o.y *= inv; o.z *= inv; o.w *= inv;
    ((float4*)orow)[d4] = o;
  }
}

extern "C" void kernel_launch(void* const* d_in, const int* in_sizes, int n_in,
                              void* d_out, int out_size, void* d_ws, size_t ws_size,
                              hipStream_t stream) {
  const float* x    = (const float*)d_in[0];
  const float* edge = (const float*)d_in[1];
  const unsigned char* mask = (const unsigned char*)d_in[2];
  const float* wq   = (const float*)d_in[3];
  const float* wk   = (const float*)d_in[4];
  const float* wv   = (const float*)d_in[5];
  const float* wo   = (const float*)d_in[6];
  const float* wo_b = (const float*)d_in[7];
  const float* we   = (const float*)d_in[8];
  const float* we_b = (const float*)d_in[9];
  const float* g1   = (const float*)d_in[10];
  const float* b1n  = (const float*)d_in[11];
  const float* g2   = (const float*)d_in[12];
  const float* b2n  = (const float*)d_in[13];
  const float* w1   = (const float*)d_in[14];
  const float* b1   = (const float*)d_in[15];
  const float* w2   = (const float*)d_in[16];
  const float* b2   = (const float*)d_in[17];
  float* out = (float*)d_out;
  float* ws  = (float*)d_ws;

  const size_t U = (size_t)M_ROWS * D_MODEL;  // 2,097,152 floats = 8 MiB
  float* xn   = ws;            // unit 0 (also reused as xn2)
  float* q    = ws + 1*U;      // unit 1
  float* k    = ws + 2*U;      // unit 2
  float* v    = ws + 3*U;      // unit 3
  float* ao   = ws + 4*U;      // unit 4
  float* x2   = ws + 5*U;      // unit 5
  float* pacc = ws + 6*U;      // units 6..9 (32 MiB) during attention
  float* hbuf = ws + 6*U;      // units 6..9 reused for FFN hidden
  float* pm   = ws + 10*U;
  float* pl   = ws + 10*U + PAIRS * JSPLIT;
  // total ws use: 10U + 2*131072 floats  ~= 85 MB

  // 1) LN1
  ln_kernel<<<M_ROWS / 4, 256, 0, stream>>>(x, g1, b1n, xn);
  // 2-4) Q/K/V projections
  dim3 g512(M_ROWS / 128, D_MODEL / 64);
  gemm_kernel<0, false><<<g512, 256, 0, stream>>>(xn, wq, nullptr, nullptr, q, M_ROWS, D_MODEL, D_MODEL);
  gemm_kernel<0, false><<<g512, 256, 0, stream>>>(xn, wk, nullptr, nullptr, k, M_ROWS, D_MODEL, D_MODEL);
  gemm_kernel<0, false><<<g512, 256, 0, stream>>>(xn, wv, nullptr, nullptr, v, M_ROWS, D_MODEL, D_MODEL);
  // 5) fused attention (j-split partials)
  attn_kernel<<<JSPLIT * (N_SEQ / TI) * B_SZ, 256, 0, stream>>>(
      q, k, v, edge, mask, we, we_b, pm, pl, pacc);
  // 6) merge partials -> attn output [B,N,D]
  attn_merge_kernel<<<PAIRS / 256, 256, 0, stream>>>(pm, pl, pacc, ao);
  // 7) output projection + residual
  gemm_kernel<0, true><<<g512, 256, 0, stream>>>(ao, wo, wo_b, x, x2, M_ROWS, D_MODEL, D_MODEL);
  // 8) LN2
  ln_kernel<<<M_ROWS / 4, 256, 0, stream>>>(x2, g2, b2n, xn);
  // 9) FFN1 + exact GELU
  dim3 gffn1(M_ROWS / 128, D_FF / 64);
  gemm_kernel<1, false><<<gffn1, 256, 0, stream>>>(xn, w1, b1, nullptr, hbuf, M_ROWS, D_FF, D_MODEL);
  // 10) FFN2 + residual -> out
  gemm_kernel<0, true><<<g512, 256, 0, stream>>>(hbuf, w2, b2, x2, out, M_ROWS, D_MODEL, D_FF);
}

// Round 5
// 587.381 us; speedup vs baseline: 3.1130x; 3.1130x over previous
//
#include <hip/hip_runtime.h>
#include <math.h>

#define D_MODEL 512
#define N_HEADS 8
#define D_K     64
#define D_EDGE  16
#define D_FF    2048
#define B_SZ    4
#define N_SEQ   1024
#define M_ROWS  (B_SZ * N_SEQ)
#define LN_EPS  1e-5f
#define JSPLIT  4
#define ROWS_T  (B_SZ * N_HEADS * N_SEQ)   // 32768

typedef __attribute__((ext_vector_type(4))) float f32x4;
typedef __attribute__((ext_vector_type(8))) short s16x8;
typedef __attribute__((ext_vector_type(8))) unsigned short u16x8;
typedef __attribute__((ext_vector_type(4))) unsigned short u16x4;

__device__ __forceinline__ unsigned short f2bf(float f) {
  union { float f; unsigned u; } x; x.f = f;
  unsigned r = x.u + 0x7fffu + ((x.u >> 16) & 1u);   // RNE
  return (unsigned short)(r >> 16);
}
__device__ __forceinline__ float bf2f(unsigned short u) {
  union { unsigned u; float f; } x; x.u = ((unsigned)u) << 16;
  return x.f;
}
__device__ __forceinline__ float gelu_exact(float v) {
  return 0.5f * v * (1.0f + erff(v * 0.70710678118654752440f));
}

// ---------------- fused weight cast fp32 -> bf16 (wq|wk|wv | wo | w1 | w2) ----------------
__global__ __launch_bounds__(256) void cast_weights(
    const float* __restrict__ wq, const float* __restrict__ wk, const float* __restrict__ wv,
    const float* __restrict__ wo, const float* __restrict__ w1, const float* __restrict__ w2,
    unsigned short* __restrict__ wbf)
{
  const int i4 = blockIdx.x * 256 + threadIdx.x;   // float4 index, 786432 total
  const float* src; int off4;
  if (i4 < 196608) {
    const int sub = i4 >> 16;                       // 0..2
    src = (sub == 0) ? wq : ((sub == 1) ? wk : wv);
    off4 = i4 & 65535;
  } else if (i4 < 262144) { src = wo; off4 = i4 - 196608; }
  else if (i4 < 524288)   { src = w1; off4 = i4 - 262144; }
  else                    { src = w2; off4 = i4 - 524288; }
  const float4 v = ((const float4*)src)[off4];
  u16x4 p = { f2bf(v.x), f2bf(v.y), f2bf(v.z), f2bf(v.w) };
  *(u16x4*)(wbf + (size_t)i4 * 4) = p;
}

// ---------------- LayerNorm: one wave per row, bf16 out ----------------
__global__ __launch_bounds__(256) void ln_kernel(
    const float* __restrict__ x, const float* __restrict__ g,
    const float* __restrict__ bb, unsigned short* __restrict__ out)
{
  const int row  = blockIdx.x * 4 + (threadIdx.x >> 6);
  const int lane = threadIdx.x & 63;
  const float4* xr = (const float4*)(x + (size_t)row * D_MODEL);
  float4 v0 = xr[lane * 2 + 0];
  float4 v1 = xr[lane * 2 + 1];
  float s  = v0.x + v0.y + v0.z + v0.w + v1.x + v1.y + v1.z + v1.w;
  float ss = v0.x*v0.x + v0.y*v0.y + v0.z*v0.z + v0.w*v0.w
           + v1.x*v1.x + v1.y*v1.y + v1.z*v1.z + v1.w*v1.w;
  #pragma unroll
  for (int off = 32; off >= 1; off >>= 1) {
    s  += __shfl_xor(s, off);
    ss += __shfl_xor(ss, off);
  }
  const float mu  = s * (1.0f / D_MODEL);
  const float var = ss * (1.0f / D_MODEL) - mu * mu;
  const float r   = rsqrtf(var + LN_EPS);
  const float4* gp = (const float4*)g;
  const float4* bp = (const float4*)bb;
  float4 g0 = gp[lane*2+0], g1v = gp[lane*2+1];
  float4 b0 = bp[lane*2+0], b1v = bp[lane*2+1];
  u16x4 oa = { f2bf((v0.x - mu) * r * g0.x + b0.x),
               f2bf((v0.y - mu) * r * g0.y + b0.y),
               f2bf((v0.z - mu) * r * g0.z + b0.z),
               f2bf((v0.w - mu) * r * g0.w + b0.w) };
  u16x4 ob = { f2bf((v1.x - mu) * r * g1v.x + b1v.x),
               f2bf((v1.y - mu) * r * g1v.y + b1v.y),
               f2bf((v1.z - mu) * r * g1v.z + b1v.z),
               f2bf((v1.w - mu) * r * g1v.w + b1v.w) };
  unsigned short* orow = out + (size_t)row * D_MODEL + lane * 8;
  *(u16x4*)(orow)     = oa;
  *(u16x4*)(orow + 4) = ob;
}

// ---------------- bf16 MFMA GEMM: C[4096][Nout] = A[4096][K] @ W[Nout][K]^T ----------------
// BM=128, BN=64, BK=64, 256 thr = 4 waves, wave computes 32x64 (2x4 16x16 frags).
template<int ACT, int RES, int OBF, int HB>
__global__ __launch_bounds__(256, 4) void gemm_bf16(
    const unsigned short* __restrict__ A, const unsigned short* __restrict__ W,
    const float* __restrict__ bias, const float* __restrict__ res,
    void* __restrict__ Cv, int Nout, int K)
{
  __shared__ unsigned short As[128 * 64];
  __shared__ unsigned short Ws[64 * 64];
  const int tid  = threadIdx.x;
  const int w    = tid >> 6;
  const int lane = tid & 63;
  const int g    = lane >> 4;
  const int c    = lane & 15;
  const int row0 = blockIdx.x * 128;
  const int col0 = blockIdx.y * 64;
  const f32x4 z = { 0.f, 0.f, 0.f, 0.f };
  f32x4 acc[2][4];
  #pragma unroll
  for (int fm = 0; fm < 2; ++fm)
    #pragma unroll
    for (int fn = 0; fn < 4; ++fn) acc[fm][fn] = z;

  for (int k0 = 0; k0 < K; k0 += 64) {
    #pragma unroll
    for (int i = 0; i < 4; ++i) {
      const int flat = i * 256 + tid;
      __builtin_amdgcn_global_load_lds(
          (const __attribute__((address_space(1))) void*)(A + (size_t)(row0 + (flat >> 3)) * K + k0 + (flat & 7) * 8),
          (__attribute__((address_space(3))) void*)(&As[flat * 8]), 16, 0, 0);
    }
    #pragma unroll
    for (int i = 0; i < 2; ++i) {
      const int flat = i * 256 + tid;
      __builtin_amdgcn_global_load_lds(
          (const __attribute__((address_space(1))) void*)(W + (size_t)(col0 + (flat >> 3)) * K + k0 + (flat & 7) * 8),
          (__attribute__((address_space(3))) void*)(&Ws[flat * 8]), 16, 0, 0);
    }
    __syncthreads();
    #pragma unroll
    for (int kk = 0; kk < 2; ++kk) {
      const s16x8 a0 = *(const s16x8*)&As[(w * 32 + c) * 64 + kk * 32 + 8 * g];
      const s16x8 a1 = *(const s16x8*)&As[(w * 32 + 16 + c) * 64 + kk * 32 + 8 * g];
      #pragma unroll
      for (int fn = 0; fn < 4; ++fn) {
        const s16x8 bfr = *(const s16x8*)&Ws[(fn * 16 + c) * 64 + kk * 32 + 8 * g];
        acc[0][fn] = __builtin_amdgcn_mfma_f32_16x16x32_bf16(a0, bfr, acc[0][fn], 0, 0, 0);
        acc[1][fn] = __builtin_amdgcn_mfma_f32_16x16x32_bf16(a1, bfr, acc[1][fn], 0, 0, 0);
      }
    }
    __syncthreads();
  }

  #pragma unroll
  for (int fn = 0; fn < 4; ++fn) {
    const int cc = col0 + fn * 16 + c;
    const float bv = HB ? bias[cc] : 0.0f;
    #pragma unroll
    for (int fm = 0; fm < 2; ++fm) {
      #pragma unroll
      for (int r = 0; r < 4; ++r) {
        const int rr = row0 + w * 32 + fm * 16 + 4 * g + r;
        float v = acc[fm][fn][r] + bv;
        if (ACT) v = gelu_exact(v);
        if (RES) v += res[(size_t)rr * Nout + cc];
        if (OBF) ((unsigned short*)Cv)[(size_t)rr * Nout + cc] = f2bf(v);
        else     ((float*)Cv)[(size_t)rr * Nout + cc] = v;
      }
    }
  }
}

// ---------------- V transpose: qkv[:,1024:1536] -> vT[b][h][64][1024] ----------------
__global__ __launch_bounds__(256) void transpose_v(
    const unsigned short* __restrict__ qkv, unsigned short* __restrict__ vT)
{
  const int bid = blockIdx.x;          // b*128 + h*16 + jt
  const int jt = bid & 15, h = (bid >> 4) & 7, b = bid >> 7;
  __shared__ unsigned short t[64][72];
  const int tid = threadIdx.x;
  #pragma unroll
  for (int itr = 0; itr < 2; ++itr) {
    const int flat = itr * 256 + tid;
    const int j = flat >> 3, ch = flat & 7;
    *(u16x8*)&t[j][ch * 8] =
        *(const u16x8*)(qkv + (size_t)(b * 1024 + jt * 64 + j) * 1536 + 1024 + h * 64 + ch * 8);
  }
  __syncthreads();
  #pragma unroll
  for (int itr = 0; itr < 2; ++itr) {
    const int flat = itr * 256 + tid;
    const int dd = flat >> 3, ch = flat & 7;
    u16x8 v;
    #pragma unroll
    for (int e = 0; e < 8; ++e) v[e] = t[ch * 8 + e][dd];
    *(u16x8*)(vT + (size_t)((b * 8 + h) * 64 + dd) * 1024 + jt * 64 + ch * 8) = v;
  }
}

// ---------------- MFMA flash attention with shared edge bias ----------------
// 512 thr = 8 waves = 8 heads; block = (b, i-tile 32, j-split). All 8 heads share
// one cooperatively computed bias tile (edge read exactly once from HBM).
// Q/K frags direct from qkv (K-contiguous); V frags direct from vT; P via per-wave LDS.
__global__ __launch_bounds__(512, 4) void attn_kernel(
    const unsigned short* __restrict__ qkv, const unsigned short* __restrict__ vT,
    const float* __restrict__ edge, const unsigned char* __restrict__ mask,
    const float* __restrict__ we, const float* __restrict__ web,
    float* __restrict__ pm, float* __restrict__ pl, float* __restrict__ pacc)
{
  __shared__ unsigned short bias_s[8][32][40];  // [h][i][j] bf16, padded
  __shared__ unsigned short p_s[8][32][40];     // per-wave P tile [i][j] bf16, padded
  __shared__ float we_s[8][16];
  __shared__ float web_s[8];

  // batch -> XCD-pair swizzle (bid%8 assumed round-robin over 8 XCDs):
  const int bid   = blockIdx.x;
  const int b     = (bid & 7) >> 1;
  const int local = ((bid >> 3) << 1) | (bid & 1);   // 0..127
  const int split = local & 3;
  const int it    = local >> 2;                      // 0..31
  const int i0    = it * 32;
  const int tid   = threadIdx.x;
  const int h     = tid >> 6;
  const int lane  = tid & 63;
  const int g     = lane >> 4;
  const int c     = lane & 15;

  if (tid < 128) we_s[tid >> 4][tid & 15] = we[tid];
  if (tid < 8)   web_s[tid] = web[tid];

  // Q fragments (held for whole block)
  s16x8 qf[2][2];
  #pragma unroll
  for (int fm = 0; fm < 2; ++fm)
    #pragma unroll
    for (int kk = 0; kk < 2; ++kk)
      qf[fm][kk] = *(const s16x8*)(qkv + (size_t)(b * 1024 + i0 + fm * 16 + c) * 1536 + h * 64 + kk * 32 + 8 * g);

  const f32x4 z = { 0.f, 0.f, 0.f, 0.f };
  f32x4 o[2][4];
  #pragma unroll
  for (int fm = 0; fm < 2; ++fm)
    #pragma unroll
    for (int fd = 0; fd < 4; ++fd) o[fm][fd] = z;
  float mreg[2][4], lreg[2][4];
  #pragma unroll
  for (int fm = 0; fm < 2; ++fm)
    #pragma unroll
    for (int r = 0; r < 4; ++r) { mreg[fm][r] = -1e30f; lreg[fm][r] = 0.f; }

  for (int jc = 0; jc < 8; ++jc) {
    const int j0 = split * 256 + jc * 32;
    __syncthreads();   // bias_s free for rewrite (and we_s ready on iter 0)
    // --- cooperative edge-bias tile: 32i x 32j for all 8 heads ---
    {
      const int pi  = tid >> 4;            // 0..31
      const int pjb = (tid & 15) * 2;      // even j
      #pragma unroll
      for (int pp = 0; pp < 2; ++pp) {
        const int pj = pjb + pp;
        const int j  = j0 + pj;
        const float4* ep = (const float4*)(edge +
            ((((size_t)b * N_SEQ) + (i0 + pi)) * N_SEQ + j) * D_EDGE);
        const float4 e0 = ep[0], e1 = ep[1], e2 = ep[2], e3 = ep[3];
        const float mk = mask[b * N_SEQ + j] ? 0.0f : -1e30f;
        #pragma unroll
        for (int hh = 0; hh < 8; ++hh) {
          const float* wv = we_s[hh];
          const float d =
              e0.x*wv[0]  + e0.y*wv[1]  + e0.z*wv[2]  + e0.w*wv[3]
            + e1.x*wv[4]  + e1.y*wv[5]  + e1.z*wv[6]  + e1.w*wv[7]
            + e2.x*wv[8]  + e2.y*wv[9]  + e2.z*wv[10] + e2.w*wv[11]
            + e3.x*wv[12] + e3.y*wv[13] + e3.z*wv[14] + e3.w*wv[15];
          bias_s[hh][pi][pj] = f2bf(d + web_s[hh] + mk);
        }
      }
    }
    __syncthreads();   // bias ready

    // --- S = Q K^T (per wave / head) ---
    f32x4 s[2][2];
    s[0][0] = z; s[0][1] = z; s[1][0] = z; s[1][1] = z;
    #pragma unroll
    for (int fn = 0; fn < 2; ++fn)
      #pragma unroll
      for (int kk = 0; kk < 2; ++kk) {
        const s16x8 kf = *(const s16x8*)(qkv +
            (size_t)(b * 1024 + j0 + fn * 16 + c) * 1536 + 512 + h * 64 + kk * 32 + 8 * g);
        #pragma unroll
        for (int fm = 0; fm < 2; ++fm)
          s[fm][fn] = __builtin_amdgcn_mfma_f32_16x16x32_bf16(qf[fm][kk], kf, s[fm][fn], 0, 0, 0);
      }

    // --- scale + bias + online softmax (row = fm*16 + 4g + r, cols on 16 lanes x 2 frags) ---
    #pragma unroll
    for (int fm = 0; fm < 2; ++fm) {
      #pragma unroll
      for (int r = 0; r < 4; ++r) {
        const int irow = fm * 16 + 4 * g + r;
        const float s0 = s[fm][0][r] * 0.125f + bf2f(bias_s[h][irow][c]);
        const float s1 = s[fm][1][r] * 0.125f + bf2f(bias_s[h][irow][16 + c]);
        float v = fmaxf(s0, s1);
        v = fmaxf(v, __shfl_xor(v, 1));
        v = fmaxf(v, __shfl_xor(v, 2));
        v = fmaxf(v, __shfl_xor(v, 4));
        v = fmaxf(v, __shfl_xor(v, 8));
        const float nm    = fmaxf(mreg[fm][r], v);
        const float alpha = __expf(mreg[fm][r] - nm);
        mreg[fm][r] = nm;
        const float p0 = __expf(s0 - nm);
        const float p1 = __expf(s1 - nm);
        lreg[fm][r] = lreg[fm][r] * alpha + p0 + p1;
        #pragma unroll
        for (int fd = 0; fd < 4; ++fd) o[fm][fd][r] *= alpha;
        p_s[h][irow][c]      = f2bf(p0);
        p_s[h][irow][16 + c] = f2bf(p1);
      }
    }

    // --- O += P V  (P A-frags from per-wave LDS; V B-frags from global vT) ---
    s16x8 pa[2];
    #pragma unroll
    for (int fm = 0; fm < 2; ++fm)
      pa[fm] = *(const s16x8*)&p_s[h][fm * 16 + c][8 * g];
    #pragma unroll
    for (int fd = 0; fd < 4; ++fd) {
      const s16x8 vf = *(const s16x8*)(vT +
          (size_t)((b * 8 + h) * 64 + fd * 16 + c) * 1024 + j0 + 8 * g);
      #pragma unroll
      for (int fm = 0; fm < 2; ++fm)
        o[fm][fd] = __builtin_amdgcn_mfma_f32_16x16x32_bf16(pa[fm], vf, o[fm][fd], 0, 0, 0);
    }
  }

  // --- epilogue: write partial O, m, l ---
  #pragma unroll
  for (int fm = 0; fm < 2; ++fm) {
    #pragma unroll
    for (int r = 0; r < 4; ++r) {
      float lv = lreg[fm][r];
      lv += __shfl_xor(lv, 1);
      lv += __shfl_xor(lv, 2);
      lv += __shfl_xor(lv, 4);
      lv += __shfl_xor(lv, 8);
      const int row = ((split * B_SZ + b) * N_HEADS + h) * N_SEQ + i0 + fm * 16 + 4 * g + r;
      #pragma unroll
      for (int fd = 0; fd < 4; ++fd)
        pacc[(size_t)row * 64 + fd * 16 + c] = o[fm][fd][r];
      if (c == 0) { pm[row] = mreg[fm][r]; pl[row] = lv; }
    }
  }
}

// ---------------- merge JSPLIT partials -> ao (bf16) ----------------
__global__ __launch_bounds__(256) void merge_kernel(
    const float* __restrict__ pm, const float* __restrict__ pl,
    const float* __restrict__ pacc, unsigned short* __restrict__ ao)
{
  const int row = blockIdx.x * 4 + (threadIdx.x >> 6);   // (b*8+h)*1024 + i
  const int d   = threadIdx.x & 63;
  float ms[JSPLIT], ls[JSPLIT];
  float M = -3e38f;
  #pragma unroll
  for (int s2 = 0; s2 < JSPLIT; ++s2) {
    ms[s2] = pm[s2 * ROWS_T + row];
    ls[s2] = pl[s2 * ROWS_T + row];
    M = fmaxf(M, ms[s2]);
  }
  float acc = 0.f, inv = 0.f;
  if (M > -1e29f) {
    float L = 0.f;
    #pragma unroll
    for (int s2 = 0; s2 < JSPLIT; ++s2) {
      const float wgt = __expf(ms[s2] - M);
      L += ls[s2] * wgt;
      acc += wgt * pacc[((size_t)s2 * ROWS_T + row) * 64 + d];
    }
    inv = 1.0f / L;
  }
  const int b2 = row >> 13, h2 = (row >> 10) & 7, i2 = row & 1023;
  ao[(size_t)(b2 * 1024 + i2) * 512 + h2 * 64 + d] = f2bf(acc * inv);
}

extern "C" void kernel_launch(void* const* d_in, const int* in_sizes, int n_in,
                              void* d_out, int out_size, void* d_ws, size_t ws_size,
                              hipStream_t stream) {
  const float* x    = (const float*)d_in[0];
  const float* edge = (const float*)d_in[1];
  const unsigned char* mask = (const unsigned char*)d_in[2];
  const float* wq   = (const float*)d_in[3];
  const float* wk   = (const float*)d_in[4];
  const float* wv   = (const float*)d_in[5];
  const float* wo   = (const float*)d_in[6];
  const float* wo_b = (const float*)d_in[7];
  const float* we   = (const float*)d_in[8];
  const float* we_b = (const float*)d_in[9];
  const float* g1   = (const float*)d_in[10];
  const float* b1n  = (const float*)d_in[11];
  const float* g2   = (const float*)d_in[12];
  const float* b2n  = (const float*)d_in[13];
  const float* w1   = (const float*)d_in[14];
  const float* b1   = (const float*)d_in[15];
  const float* w2   = (const float*)d_in[16];
  const float* b2   = (const float*)d_in[17];
  float* out = (float*)d_out;
  char* ws = (char*)d_ws;

  const size_t MB = 1048576;
  unsigned short* xn_bf  = (unsigned short*)(ws + 0 * MB);    // 4 MiB  [4096][512]
  unsigned short* qkv_bf = (unsigned short*)(ws + 4 * MB);    // 12 MiB [4096][1536]
  unsigned short* vT     = (unsigned short*)(ws + 16 * MB);   // 4 MiB  [4][8][64][1024]
  unsigned short* ao_bf  = (unsigned short*)(ws + 20 * MB);   // 4 MiB  [4096][512]
  float*          x2     = (float*)(ws + 24 * MB);            // 8 MiB  [4096][512]
  unsigned short* wbf    = (unsigned short*)(ws + 32 * MB);   // 6 MiB  qkv|wo|w1|w2
  float*          pm     = (float*)(ws + 38 * MB);            // 0.5 MiB
  float*          pl     = (float*)(ws + 38 * MB + 524288);   // 0.5 MiB
  float*          pacc   = (float*)(ws + 41 * MB);            // 32 MiB
  unsigned short* hbuf   = (unsigned short*)(ws + 41 * MB);   // 16 MiB (overlays pacc; used after merge)

  unsigned short* wqkv_bf = wbf;
  unsigned short* wo_bf   = wbf + 786432;
  unsigned short* w1_bf   = wbf + 1048576;
  unsigned short* w2_bf   = wbf + 2097152;

  // 1) weight casts
  cast_weights<<<3072, 256, 0, stream>>>(wq, wk, wv, wo, w1, w2, wbf);
  // 2) LN1 -> bf16
  ln_kernel<<<M_ROWS / 4, 256, 0, stream>>>(x, g1, b1n, xn_bf);
  // 3) fused QKV projection: [4096][512] @ [1536][512]^T -> qkv_bf
  {
    dim3 grid(M_ROWS / 128, 1536 / 64);
    gemm_bf16<0, 0, 1, 0><<<grid, 256, 0, stream>>>(xn_bf, wqkv_bf, nullptr, nullptr, qkv_bf, 1536, 512);
  }
  // 4) V transpose
  transpose_v<<<512, 256, 0, stream>>>(qkv_bf, vT);
  // 5) flash attention partials
  attn_kernel<<<512, 512, 0, stream>>>(qkv_bf, vT, edge, mask, we, we_b, pm, pl, pacc);
  // 6) merge -> ao (bf16)
  merge_kernel<<<ROWS_T / 4, 256, 0, stream>>>(pm, pl, pacc, ao_bf);
  // 7) output projection + residual -> x2 (f32)
  {
    dim3 grid(M_ROWS / 128, 512 / 64);
    gemm_bf16<0, 1, 0, 1><<<grid, 256, 0, stream>>>(ao_bf, wo_bf, wo_b, x, (void*)x2, 512, 512);
  }
  // 8) LN2 -> bf16
  ln_kernel<<<M_ROWS / 4, 256, 0, stream>>>(x2, g2, b2n, xn_bf);
  // 9) FFN1 + exact GELU -> hbuf (bf16)
  {
    dim3 grid(M_ROWS / 128, 2048 / 64);
    gemm_bf16<1, 0, 1, 1><<<grid, 256, 0, stream>>>(xn_bf, w1_bf, b1, nullptr, hbuf, 2048, 512);
  }
  // 10) FFN2 + residual -> out (f32)
  {
    dim3 grid(M_ROWS / 128, 512 / 64);
    gemm_bf16<0, 1, 0, 1><<<grid, 256, 0, stream>>>(hbuf, w2_bf, b2, x2, (void*)out, 512, 2048);
  }
}